// Round 21
// baseline (348.397 us; speedup 1.0000x reference)
//
#include <hip/hip_runtime.h>
#include <cstdint>
#include <cstddef>

typedef __attribute__((ext_vector_type(8))) short bf16x8;
typedef __attribute__((ext_vector_type(4))) float f32x4;
typedef __attribute__((ext_vector_type(4))) unsigned int u32x4;
typedef unsigned short u16;

#define H1_ROW_B   1920                 /* packed row: 30x * 32ci * 2B     */
#define H1_BATCH   (30 * 30 * 960)      /* elems per batch (864000)        */
#define LDS_STRIDE 1952                 /* 1920 + 32: 488 dw = 8-bank row shift */
#define OUT_CSTR   21952                /* 28*28*28                        */

__device__ __forceinline__ u16 f2bf(float f) {
    union { float f; unsigned u; } v; v.f = f;
    unsigned r = v.u + 0x7FFF + ((v.u >> 16) & 1);   // RNE
    return (u16)(r >> 16);
}

__device__ __forceinline__ void fma4(float4& a, float s, const float4& w) {
    a.x = fmaf(s, w.x, a.x);
    a.y = fmaf(s, w.y, a.y);
    a.z = fmaf(s, w.z, a.z);
    a.w = fmaf(s, w.w, a.w);
}

__device__ __forceinline__ void gld_lds(const char* src, unsigned char* dst) {
    __builtin_amdgcn_global_load_lds(
        (const __attribute__((address_space(1))) void*)src,
        (__attribute__((address_space(3))) void*)dst, 16, 0, 0);
}

// ---------------- conv1 + bias + relu -> bf16 h1 [bl][z][y][30x][32ci] ----
// x staged in LDS (one coalesced pass); weights in registers (L1-broadcast).
__global__ __launch_bounds__(256) void conv1_relu(
    const float* __restrict__ x, const float* __restrict__ w1,
    const float* __restrict__ b1, u16* __restrict__ h1, int b0)
{
    __shared__ float xs[3 * 8 * 32];     // [zp][y][x] f32, 3 KB

    const int z   = blockIdx.x;        // 0..29
    const int yt  = blockIdx.y;        // 0..4
    const int bl  = blockIdx.z;
    const int b   = b0 + bl;
    const int tid = threadIdx.x;
    const int y0  = yt * 6;

    // stage x[z..z+2][y0..y0+7][0..31] (768 f32) : 192 threads x float4
    if (tid < 192) {
        const int idx = tid * 4;         // 0..764
        const int zp  = idx >> 8;
        const int rem = idx & 255;
        const int yy  = rem >> 5;
        const int xx  = rem & 31;
        const float4 v = *reinterpret_cast<const float4*>(
            x + (size_t)b * 32768 + ((size_t)(z + zp) * 32 + (y0 + yy)) * 32 + xx);
        *reinterpret_cast<float4*>(&xs[idx]) = v;
    }

    const int c4   = tid & 7;          // ci c4*4 .. +3
    const int slot = tid >> 3;         // 0..31; active slots 0..29

    // weights -> registers (L1-broadcast: all waves read the same 3.5 KB)
    float4 wr[27];
#pragma unroll
    for (int t = 0; t < 27; ++t)
        wr[t] = *reinterpret_cast<const float4*>(w1 + t * 32 + c4 * 4);
    const float4 bias = *reinterpret_cast<const float4*>(b1 + c4 * 4);

    __syncthreads();

    u16* h1b = h1 + (size_t)bl * H1_BATCH;

    if (slot < 30) {
#pragma unroll
        for (int j = 0; j < 3; ++j) {
            const int p  = slot + 30 * j;     // 0..89 pair index
            const int yy = p / 15;
            const int xx = (p - yy * 15) * 2; // 0,2,..,28 (8B aligned)
            const int y  = y0 + yy;

            float4 acc0 = bias, acc1 = bias;
#pragma unroll
            for (int kd = 0; kd < 3; ++kd) {
#pragma unroll
                for (int kh = 0; kh < 3; ++kh) {
                    const float* row = &xs[((kd * 8) + (yy + kh)) * 32 + xx];
                    const float2 v01 = *reinterpret_cast<const float2*>(row);
                    const float2 v23 = *reinterpret_cast<const float2*>(row + 2);
                    const int t = (kd * 3 + kh) * 3;
                    fma4(acc0, v01.x, wr[t + 0]);
                    fma4(acc0, v01.y, wr[t + 1]);
                    fma4(acc0, v23.x, wr[t + 2]);
                    fma4(acc1, v01.y, wr[t + 0]);
                    fma4(acc1, v23.x, wr[t + 1]);
                    fma4(acc1, v23.y, wr[t + 2]);
                }
            }
            ushort4 s0, s1;
            s0.x = f2bf(fmaxf(acc0.x, 0.f)); s0.y = f2bf(fmaxf(acc0.y, 0.f));
            s0.z = f2bf(fmaxf(acc0.z, 0.f)); s0.w = f2bf(fmaxf(acc0.w, 0.f));
            s1.x = f2bf(fmaxf(acc1.x, 0.f)); s1.y = f2bf(fmaxf(acc1.y, 0.f));
            s1.z = f2bf(fmaxf(acc1.z, 0.f)); s1.w = f2bf(fmaxf(acc1.w, 0.f));
            u16* dst = h1b + ((size_t)(z * 30 + y) * 30 + xx) * 32 + c4 * 4;
            *reinterpret_cast<ushort4*>(dst)      = s0;
            *reinterpret_cast<ushort4*>(dst + 32) = s1;
        }
    }
}

// ---------------- pack w2 fp32 DHWIO -> bf16 B-fragments ------------------
// wB[((tap*4 + nt)*64 + lane)*8 + j] = bf16(w2[tap][(lane>>4)*8 + j][nt*16 + (lane&15)])
__global__ __launch_bounds__(256) void pack_w2(
    const float* __restrict__ w2, u16* __restrict__ wB)
{
    const int tap = blockIdx.x;      // 0..26
    const int tid = threadIdx.x;
    const int nt = tid >> 6;
    const int l  = tid & 63;
    const int r = l & 15, q = l >> 4;
    u16* dst = wB + ((size_t)(tap * 4 + nt) * 64 + l) * 8;
#pragma unroll
    for (int j = 0; j < 8; ++j)
        dst[j] = f2bf(w2[(size_t)(tap * 32 + q * 8 + j) * 64 + nt * 16 + r]);
}

// ---------------- conv2: 8-wave N-split, DUAL A-SOURCE --------------------
// r18 geometry; NEW: nh=0 waves read A from LDS (r18 path, asm counted-vmcnt
// B prefetch); nh=1 waves read A DIRECTLY FROM GLOBAL h1 (L1/L2 path, plain
// compiler-scheduled loads for both A and B). The two wave groups' redundant
// A-fragment reads (identical data) now travel different pipes:
//   LDS pipe 93% -> ~46%; L1 path ~47%; matrix ~19% — no pipe saturated.
// Whole-wave divergence, no barriers inside the divergent region.
__global__ __launch_bounds__(512, 4) void conv2_mfma(
    const u16* __restrict__ h1, const u16* __restrict__ wB,
    const float* __restrict__ b2, float* __restrict__ out, int b0)
{
    __shared__ __align__(16) unsigned char smem[36 * LDS_STRIDE];  // 70272 B

    const int g   = gridDim.x;
    const int bid = blockIdx.x;
    const int lb  = (g % 8 == 0) ? ((bid & 7) * (g >> 3) + (bid >> 3)) : bid;

    const int t0  = lb % 49;
    const int bl  = lb / 49;
    const int yg  = t0 % 7;
    const int zt  = t0 / 7;

    const int b  = b0 + bl;
    const int y0 = yg * 4, z0 = zt * 4;
    const int tid = threadIdx.x;
    const int wv  = tid >> 6;       // 0..7
    const int l   = tid & 63;
    const int zw  = wv >> 1;        // wave z offset 0..3
    const int nh  = wv & 1;         // wave N half
    const int r = l & 15, q = l >> 4;
    const int yl = r >> 2, xg = r & 3;

    const char* wBl = (const char*)wB + nh * 2048 + l * 16;
    const char* gbase = (const char*)(h1 + (size_t)bl * H1_BATCH);

    // ---- stage A: 36 rows x 1920 B, chunks at 0 and 896 (128 B overlap) --
    {
        for (int c = wv; c < 72; c += 8) {           // wave-uniform chunks
            const int rid = c >> 1, half = c & 1;
            const int zz = rid / 6, yy = rid - zz * 6;
            const char* src = gbase
                + (size_t)((z0 + zz) * 30 + (y0 + yy)) * H1_ROW_B
                + half * 896 + l * 16;
            unsigned char* dst = smem + rid * LDS_STRIDE + half * 896 + l * 16;
            gld_lds(src, dst);
        }
    }
    __syncthreads();   // drains staging (vmcnt(0)) + publishes LDS

    // ---- accumulators init with bias (co = nh*32 + nt*16 + r) ----
    f32x4 acc[7][2];
    {
        const float bv0 = b2[nh * 32 + r];
        const float bv1 = b2[nh * 32 + 16 + r];
#pragma unroll
        for (int mt = 0; mt < 7; ++mt) {
            acc[mt][0] = (f32x4){bv0, bv0, bv0, bv0};
            acc[mt][1] = (f32x4){bv1, bv1, bv1, bv1};
        }
    }

    if (nh == 0) {
        // ================= LDS-A path (r18 verbatim) =================
        const unsigned char* aBase =
            smem + (zw * 6 + yl) * LDS_STRIDE + xg * 64 + q * 16;

        u32x4 Bs[3][2];
#define B_LOAD(slot, t)                                                        \
    { const char* p_ = wBl + (size_t)(t) * 4096;                               \
      asm volatile("global_load_dwordx4 %0, %2, off\n\t"                       \
                   "global_load_dwordx4 %1, %2, off offset:1024"               \
                   : "=&v"(Bs[slot][0]), "=&v"(Bs[slot][1]) : "v"(p_)); }

        B_LOAD(0, 0)
        B_LOAD(1, 1)

#pragma unroll
        for (int tap = 0; tap < 27; ++tap) {
            const int cur = tap % 3;

            if (tap < 25) B_LOAD((tap + 2) % 3, tap + 2)

            if (tap < 25)       asm volatile("s_waitcnt vmcnt(4)");
            else if (tap == 25) asm volatile("s_waitcnt vmcnt(2)");
            else                asm volatile("s_waitcnt vmcnt(0)");

            asm volatile("" : "+v"(Bs[cur][0]), "+v"(Bs[cur][1]));
            const bf16x8 B0 = __builtin_bit_cast(bf16x8, Bs[cur][0]);
            const bf16x8 B1 = __builtin_bit_cast(bf16x8, Bs[cur][1]);

            const int kd = tap / 9;
            const int kh = (tap - kd * 9) / 3;
            const int kw = tap - kd * 9 - kh * 3;
            const unsigned char* ap = aBase + (kd * 6 + kh) * LDS_STRIDE + kw * 64;

#pragma unroll
            for (int mt = 0; mt < 7; ++mt) {
                const bf16x8 a = *reinterpret_cast<const bf16x8*>(ap + mt * 256);
                acc[mt][0] = __builtin_amdgcn_mfma_f32_16x16x32_bf16(a, B0, acc[mt][0], 0, 0, 0);
                acc[mt][1] = __builtin_amdgcn_mfma_f32_16x16x32_bf16(a, B1, acc[mt][1], 0, 0, 0);
            }
        }
#undef B_LOAD
    } else {
        // ================= global-A path (L1/L2) =================
        // Same fragment data as the LDS tile, read from h1 directly.
        // Plain loads: compiler schedules waitcnt + pipelining across the
        // fully-unrolled tap loop (no asm vmcnt interference).
        const char* aGlob = gbase
            + (size_t)((z0 + zw) * 30 + (y0 + yl)) * H1_ROW_B
            + xg * 64 + q * 16;

#pragma unroll
        for (int tap = 0; tap < 27; ++tap) {
            const int kd = tap / 9;
            const int kh = (tap - kd * 9) / 3;
            const int kw = tap - kd * 9 - kh * 3;
            const char* ap = aGlob
                + (size_t)(kd * 30 + kh) * H1_ROW_B + kw * 64;
            const char* bp = wBl + (size_t)tap * 4096;

            const bf16x8 B0 = *reinterpret_cast<const bf16x8*>(bp);
            const bf16x8 B1 = *reinterpret_cast<const bf16x8*>(bp + 1024);

#pragma unroll
            for (int mt = 0; mt < 7; ++mt) {
                const bf16x8 a = *reinterpret_cast<const bf16x8*>(ap + mt * 256);
                acc[mt][0] = __builtin_amdgcn_mfma_f32_16x16x32_bf16(a, B0, acc[mt][0], 0, 0, 0);
                acc[mt][1] = __builtin_amdgcn_mfma_f32_16x16x32_bf16(a, B1, acc[mt][1], 0, 0, 0);
            }
        }
    }

    // ---- epilogue (nt OUTER, mt INNER): lane (r,q): co = nh*32+nt*16+r,
    // y = y0+q, x = mt*4..+3 — 7 consecutive 16B stores per lane = 112 B run
    const int z = z0 + zw;
    float* ob = out + ((size_t)b * 64 + nh * 32 + r) * OUT_CSTR
                    + (size_t)z * 784 + (size_t)(y0 + q) * 28;
#pragma unroll
    for (int nt = 0; nt < 2; ++nt) {
        float* obn = ob + (size_t)nt * 16 * OUT_CSTR;
#pragma unroll
        for (int mt = 0; mt < 7; ++mt) {
            const f32x4 v = acc[mt][nt];
            float4 st;
            st.x = fmaxf(v.x, 0.f);
            st.y = fmaxf(v.y, 0.f);
            st.z = fmaxf(v.z, 0.f);
            st.w = fmaxf(v.w, 0.f);
            *reinterpret_cast<float4*>(obn + mt * 4) = st;
        }
    }
}

extern "C" void kernel_launch(void* const* d_in, const int* in_sizes, int n_in,
                              void* d_out, int out_size, void* d_ws, size_t ws_size,
                              hipStream_t stream)
{
    const float* x  = (const float*)d_in[0];
    const float* w1 = (const float*)d_in[1];
    const float* b1 = (const float*)d_in[2];
    const float* w2 = (const float*)d_in[3];
    const float* b2 = (const float*)d_in[4];
    float* out = (float*)d_out;

    u16* wB = (u16*)d_ws;                               // 110,592 B packed weights
    u16* h1 = (u16*)((char*)d_ws + 131072);

    pack_w2<<<27, 256, 0, stream>>>(w2, wB);

    const size_t per_batch = (size_t)H1_BATCH * 2;      // 1,728,000 B
    size_t avail = ws_size > 131072 ? ws_size - 131072 : 0;
    int bchunk = (int)(avail / per_batch);
    if (bchunk < 1)  bchunk = 1;
    if (bchunk > 64) bchunk = 64;

    for (int b0 = 0; b0 < 64; b0 += bchunk) {
        int bc = 64 - b0;
        if (bc > bchunk) bc = bchunk;
        conv1_relu<<<dim3(30, 5, bc), 256, 0, stream>>>(x, w1, b1, h1, b0);
        conv2_mfma<<<dim3(49 * bc), 512, 0, stream>>>(h1, wB, b2, out, b0);
    }
}

// Round 22
// 256.475 us; speedup vs baseline: 1.3584x; 1.3584x over previous
//
#include <hip/hip_runtime.h>
#include <cstdint>
#include <cstddef>

typedef __attribute__((ext_vector_type(8))) short bf16x8;
typedef __attribute__((ext_vector_type(4))) float f32x4;
typedef __attribute__((ext_vector_type(4))) unsigned int u32x4;
typedef unsigned short u16;

#define H1_ROW_B   1920                 /* packed row: 30x * 32ci * 2B     */
#define H1_BATCH   (30 * 30 * 960)      /* elems per batch (864000)        */
#define LDS_STRIDE 1952                 /* 1920 + 32: 488 dw = 8-bank row shift */
#define OUT_CSTR   21952                /* 28*28*28                        */

__device__ __forceinline__ u16 f2bf(float f) {
    union { float f; unsigned u; } v; v.f = f;
    unsigned r = v.u + 0x7FFF + ((v.u >> 16) & 1);   // RNE
    return (u16)(r >> 16);
}

__device__ __forceinline__ void fma4(float4& a, float s, const float4& w) {
    a.x = fmaf(s, w.x, a.x);
    a.y = fmaf(s, w.y, a.y);
    a.z = fmaf(s, w.z, a.z);
    a.w = fmaf(s, w.w, a.w);
}

__device__ __forceinline__ void gld_lds(const char* src, unsigned char* dst) {
    __builtin_amdgcn_global_load_lds(
        (const __attribute__((address_space(1))) void*)src,
        (__attribute__((address_space(3))) void*)dst, 16, 0, 0);
}

// ---------------- conv1 + bias + relu -> bf16 h1 [bl][z][y][30x][32ci] ----
// x staged in LDS (one coalesced pass); weights in registers (L1-broadcast).
__global__ __launch_bounds__(256) void conv1_relu(
    const float* __restrict__ x, const float* __restrict__ w1,
    const float* __restrict__ b1, u16* __restrict__ h1, int b0)
{
    __shared__ float xs[3 * 8 * 32];     // [zp][y][x] f32, 3 KB

    const int z   = blockIdx.x;        // 0..29
    const int yt  = blockIdx.y;        // 0..4
    const int bl  = blockIdx.z;
    const int b   = b0 + bl;
    const int tid = threadIdx.x;
    const int y0  = yt * 6;

    // stage x[z..z+2][y0..y0+7][0..31] (768 f32) : 192 threads x float4
    if (tid < 192) {
        const int idx = tid * 4;         // 0..764
        const int zp  = idx >> 8;
        const int rem = idx & 255;
        const int yy  = rem >> 5;
        const int xx  = rem & 31;
        const float4 v = *reinterpret_cast<const float4*>(
            x + (size_t)b * 32768 + ((size_t)(z + zp) * 32 + (y0 + yy)) * 32 + xx);
        *reinterpret_cast<float4*>(&xs[idx]) = v;
    }

    const int c4   = tid & 7;          // ci c4*4 .. +3
    const int slot = tid >> 3;         // 0..31; active slots 0..29

    // weights -> registers (L1-broadcast: all waves read the same 3.5 KB)
    float4 wr[27];
#pragma unroll
    for (int t = 0; t < 27; ++t)
        wr[t] = *reinterpret_cast<const float4*>(w1 + t * 32 + c4 * 4);
    const float4 bias = *reinterpret_cast<const float4*>(b1 + c4 * 4);

    __syncthreads();

    u16* h1b = h1 + (size_t)bl * H1_BATCH;

    if (slot < 30) {
#pragma unroll
        for (int j = 0; j < 3; ++j) {
            const int p  = slot + 30 * j;     // 0..89 pair index
            const int yy = p / 15;
            const int xx = (p - yy * 15) * 2; // 0,2,..,28 (8B aligned)
            const int y  = y0 + yy;

            float4 acc0 = bias, acc1 = bias;
#pragma unroll
            for (int kd = 0; kd < 3; ++kd) {
#pragma unroll
                for (int kh = 0; kh < 3; ++kh) {
                    const float* row = &xs[((kd * 8) + (yy + kh)) * 32 + xx];
                    const float2 v01 = *reinterpret_cast<const float2*>(row);
                    const float2 v23 = *reinterpret_cast<const float2*>(row + 2);
                    const int t = (kd * 3 + kh) * 3;
                    fma4(acc0, v01.x, wr[t + 0]);
                    fma4(acc0, v01.y, wr[t + 1]);
                    fma4(acc0, v23.x, wr[t + 2]);
                    fma4(acc1, v01.y, wr[t + 0]);
                    fma4(acc1, v23.x, wr[t + 1]);
                    fma4(acc1, v23.y, wr[t + 2]);
                }
            }
            ushort4 s0, s1;
            s0.x = f2bf(fmaxf(acc0.x, 0.f)); s0.y = f2bf(fmaxf(acc0.y, 0.f));
            s0.z = f2bf(fmaxf(acc0.z, 0.f)); s0.w = f2bf(fmaxf(acc0.w, 0.f));
            s1.x = f2bf(fmaxf(acc1.x, 0.f)); s1.y = f2bf(fmaxf(acc1.y, 0.f));
            s1.z = f2bf(fmaxf(acc1.z, 0.f)); s1.w = f2bf(fmaxf(acc1.w, 0.f));
            u16* dst = h1b + ((size_t)(z * 30 + y) * 30 + xx) * 32 + c4 * 4;
            *reinterpret_cast<ushort4*>(dst)      = s0;
            *reinterpret_cast<ushort4*>(dst + 32) = s1;
        }
    }
}

// ---------------- pack w2 fp32 DHWIO -> bf16 B-fragments ------------------
// wB[((tap*4 + nt)*64 + lane)*8 + j] = bf16(w2[tap][(lane>>4)*8 + j][nt*16 + (lane&15)])
__global__ __launch_bounds__(256) void pack_w2(
    const float* __restrict__ w2, u16* __restrict__ wB)
{
    const int tap = blockIdx.x;      // 0..26
    const int tid = threadIdx.x;
    const int nt = tid >> 6;
    const int l  = tid & 63;
    const int r = l & 15, q = l >> 4;
    u16* dst = wB + ((size_t)(tap * 4 + nt) * 64 + l) * 8;
#pragma unroll
    for (int j = 0; j < 8; ++j)
        dst[j] = f2bf(w2[(size_t)(tap * 32 + q * 8 + j) * 64 + nt * 16 + r]);
}

// ---------------- conv2 implicit-GEMM MFMA, 8-wave N-split ----------------
// Best measured config (r9/r14/r18/r20): Grid 49*bc x 512 thr (XCD-swizzled).
// Block: 4z x 4y x 28x. 8 waves: wave wv -> z-plane zw=wv>>1, N-half nh.
// Per wave: 7 m-tiles x 2 n-frags (16x16x32). A in LDS (36 x 1920 B,
// stride 1952, 0-conflict). B global 2 KB/wave/tap, 2-deep, counted vmcnt.
// No setprio. 2 blocks/CU, 16 waves/CU. Epilogue nt-outer (112 B runs).
__global__ __launch_bounds__(512, 4) void conv2_mfma(
    const u16* __restrict__ h1, const u16* __restrict__ wB,
    const float* __restrict__ b2, float* __restrict__ out, int b0)
{
    __shared__ __align__(16) unsigned char smem[36 * LDS_STRIDE];  // 70272 B

    const int g   = gridDim.x;
    const int bid = blockIdx.x;
    const int lb  = (g % 8 == 0) ? ((bid & 7) * (g >> 3) + (bid >> 3)) : bid;

    const int t0  = lb % 49;
    const int bl  = lb / 49;
    const int yg  = t0 % 7;
    const int zt  = t0 / 7;

    const int b  = b0 + bl;
    const int y0 = yg * 4, z0 = zt * 4;
    const int tid = threadIdx.x;
    const int wv  = tid >> 6;       // 0..7
    const int l   = tid & 63;
    const int zw  = wv >> 1;        // wave z offset 0..3
    const int nh  = wv & 1;         // wave N half
    const int r = l & 15, q = l >> 4;
    const int yl = r >> 2, xg = r & 3;

    const char* wBl = (const char*)wB + nh * 2048 + l * 16;

    // ---- stage A: 36 rows x 1920 B, chunks at 0 and 896 (128 B overlap) --
    {
        const char* gbase = (const char*)(h1 + (size_t)bl * H1_BATCH);
        for (int c = wv; c < 72; c += 8) {           // wave-uniform chunks
            const int rid = c >> 1, half = c & 1;
            const int zz = rid / 6, yy = rid - zz * 6;
            const char* src = gbase
                + (size_t)((z0 + zz) * 30 + (y0 + yy)) * H1_ROW_B
                + half * 896 + l * 16;
            unsigned char* dst = smem + rid * LDS_STRIDE + half * 896 + l * 16;
            gld_lds(src, dst);
        }
    }
    __syncthreads();   // drains staging (vmcnt(0)) + publishes LDS

    // ---- accumulators init with bias (co = nh*32 + nt*16 + r) ----
    f32x4 acc[7][2];
    {
        const float bv0 = b2[nh * 32 + r];
        const float bv1 = b2[nh * 32 + 16 + r];
#pragma unroll
        for (int mt = 0; mt < 7; ++mt) {
            acc[mt][0] = (f32x4){bv0, bv0, bv0, bv0};
            acc[mt][1] = (f32x4){bv1, bv1, bv1, bv1};
        }
    }

    // per-lane A base: row (zw+kd)*6 + (yl+kh), x = mt*4 + xg + kw, K-qtr q
    const unsigned char* aBase =
        smem + (zw * 6 + yl) * LDS_STRIDE + xg * 64 + q * 16;

    u32x4 Bs[3][2];
#define B_LOAD(slot, t)                                                        \
    { const char* p_ = wBl + (size_t)(t) * 4096;                               \
      asm volatile("global_load_dwordx4 %0, %2, off\n\t"                       \
                   "global_load_dwordx4 %1, %2, off offset:1024"               \
                   : "=&v"(Bs[slot][0]), "=&v"(Bs[slot][1]) : "v"(p_)); }

    // 2-deep prologue (staging already drained -> vmcnt counting exact)
    B_LOAD(0, 0)
    B_LOAD(1, 1)

    // ---- barrier-free K-loop over 27 taps, fully unrolled ----
#pragma unroll
    for (int tap = 0; tap < 27; ++tap) {
        const int cur = tap % 3;

        if (tap < 25) B_LOAD((tap + 2) % 3, tap + 2)

        // after wait: taps t+1 (and t+2 if issued) remain in flight
        if (tap < 25)       asm volatile("s_waitcnt vmcnt(4)");
        else if (tap == 25) asm volatile("s_waitcnt vmcnt(2)");
        else                asm volatile("s_waitcnt vmcnt(0)");

        asm volatile("" : "+v"(Bs[cur][0]), "+v"(Bs[cur][1]));
        const bf16x8 B0 = __builtin_bit_cast(bf16x8, Bs[cur][0]);
        const bf16x8 B1 = __builtin_bit_cast(bf16x8, Bs[cur][1]);

        const int kd = tap / 9;
        const int kh = (tap - kd * 9) / 3;
        const int kw = tap - kd * 9 - kh * 3;
        const unsigned char* ap = aBase + (kd * 6 + kh) * LDS_STRIDE + kw * 64;

#pragma unroll
        for (int mt = 0; mt < 7; ++mt) {
            const bf16x8 a = *reinterpret_cast<const bf16x8*>(ap + mt * 256);
            acc[mt][0] = __builtin_amdgcn_mfma_f32_16x16x32_bf16(a, B0, acc[mt][0], 0, 0, 0);
            acc[mt][1] = __builtin_amdgcn_mfma_f32_16x16x32_bf16(a, B1, acc[mt][1], 0, 0, 0);
        }
    }
#undef B_LOAD

    // ---- epilogue (nt OUTER, mt INNER): lane (r,q): co = nh*32+nt*16+r,
    // y = y0+q, x = mt*4..+3 — 7 consecutive 16B stores per lane = 112 B run
    const int z = z0 + zw;
    float* ob = out + ((size_t)b * 64 + nh * 32 + r) * OUT_CSTR
                    + (size_t)z * 784 + (size_t)(y0 + q) * 28;
#pragma unroll
    for (int nt = 0; nt < 2; ++nt) {
        float* obn = ob + (size_t)nt * 16 * OUT_CSTR;
#pragma unroll
        for (int mt = 0; mt < 7; ++mt) {
            const f32x4 v = acc[mt][nt];
            float4 st;
            st.x = fmaxf(v.x, 0.f);
            st.y = fmaxf(v.y, 0.f);
            st.z = fmaxf(v.z, 0.f);
            st.w = fmaxf(v.w, 0.f);
            *reinterpret_cast<float4*>(obn + mt * 4) = st;
        }
    }
}

extern "C" void kernel_launch(void* const* d_in, const int* in_sizes, int n_in,
                              void* d_out, int out_size, void* d_ws, size_t ws_size,
                              hipStream_t stream)
{
    const float* x  = (const float*)d_in[0];
    const float* w1 = (const float*)d_in[1];
    const float* b1 = (const float*)d_in[2];
    const float* w2 = (const float*)d_in[3];
    const float* b2 = (const float*)d_in[4];
    float* out = (float*)d_out;

    u16* wB = (u16*)d_ws;                               // 110,592 B packed weights
    u16* h1 = (u16*)((char*)d_ws + 131072);

    pack_w2<<<27, 256, 0, stream>>>(w2, wB);

    const size_t per_batch = (size_t)H1_BATCH * 2;      // 1,728,000 B
    size_t avail = ws_size > 131072 ? ws_size - 131072 : 0;
    int bchunk = (int)(avail / per_batch);
    if (bchunk < 1)  bchunk = 1;
    if (bchunk > 64) bchunk = 64;

    for (int b0 = 0; b0 < 64; b0 += bchunk) {
        int bc = 64 - b0;
        if (bc > bchunk) bc = bchunk;
        conv1_relu<<<dim3(30, 5, bc), 256, 0, stream>>>(x, w1, b1, h1, b0);
        conv2_mfma<<<dim3(49 * bc), 512, 0, stream>>>(h1, wB, b2, out, b0);
    }
}